// Round 2
// baseline (112.241 us; speedup 1.0000x reference)
//
#include <hip/hip_runtime.h>
#include <cstdint>
#include <cstddef>

#define HH 64          // H
#define G3 192         // 3H
#define G2 128         // 2H
#define ROW 12480      // 3H*(H+1)
#define BOUNDARY (-0.01f)

__device__ __forceinline__ float sigm(float x) { return 1.0f / (1.0f + __expf(-x)); }

__device__ __forceinline__ void load_lds16(const float* g, float* l) {
    __builtin_amdgcn_global_load_lds(
        (const __attribute__((address_space(1))) void*)g,
        (__attribute__((address_space(3))) void*)l,
        16, 0, 0);
}

// Zero H_curr section, copy c_global into c_global_new section.
__global__ __launch_bounds__(256) void init_kernel(float* __restrict__ outH,
                                                   float* __restrict__ outC,
                                                   const float* __restrict__ c_global,
                                                   int fh4) {
    int idx = blockIdx.x * 256 + threadIdx.x;
    int stride = gridDim.x * 256;
    for (int k = idx; k < fh4; k += stride) {
        ((float4*)outH)[k] = make_float4(0.f, 0.f, 0.f, 0.f);
        ((float4*)outC)[k] = ((const float4*)c_global)[k];
    }
}

// One block per gathered feature.
__global__ __launch_bounds__(256) void lstm_main(
    const float* __restrict__ X, const float* __restrict__ delta,
    const float* __restrict__ Ht, const float* __restrict__ c_t,
    const float* __restrict__ W, const float* __restrict__ bias,
    const float* __restrict__ xTw, const float* __restrict__ xTb,
    const float* __restrict__ dTw, const float* __restrict__ cinw,
    const float* __restrict__ coutw, const int* __restrict__ feat_idx,
    float* __restrict__ outH, float* __restrict__ outC) {

    __shared__ float w[ROW];      // 49,920 B
    __shared__ float inp[72];     // [x, h_prev(64)]
    __shared__ float co[G3];      // cur_out

    const int t = threadIdx.x;
    const int i = feat_idx[blockIdx.x];
    const int wave = t >> 6;
    const int lane = t & 63;

    // stage cur_input
    if (t == 0) inp[0] = X[i];
    if (wave == 1) inp[1 + lane] = Ht[(size_t)i * HH + lane];

    // stage weight row: 12480 floats = 48.75 wave-loads of 64x16B
    const float* wrow = W + (size_t)i * ROW;
    for (int c = wave; c < 49; c += 4) {
        int fbase = c * 256;
        int fidx = fbase + lane * 4;
        if (fidx < ROW) load_lds16(wrow + fidx, &w[fbase]);
    }
    __syncthreads();

    // matvec: thread g computes cur_out[g] = bias + sum_h w[g][h]*inp[h]
    if (t < G3) {
        const float* wr = &w[t * 65];
        float acc = bias[(size_t)i * G3 + t];
        #pragma unroll
        for (int h = 0; h < 65; ++h) acc = fmaf(wr[h], inp[h], acc);
        co[t] = acc;
    }
    __syncthreads();

    // gate math, one thread per h
    if (t < HH) {
        const float xi = inp[0];
        const float di = delta[i];
        const float ct = c_t[t];
        const size_t i1 = (size_t)i * HH;
        const size_t i2 = (size_t)i * G2;
        const size_t i3 = (size_t)i * G3;

        float gi_pre = co[t];
        float go_pre = co[HH + t];
        float gc = tanhf(co[2 * HH + t]);

        float xm1 = fmaf(xTw[i2 + t], xi, xTb[i2 + t]);
        float xm2 = fmaf(xTw[i2 + HH + t], xi, xTb[i2 + HH + t]);

        float dw1 = dTw[i3 + t];
        float dw2 = dTw[i3 + HH + t];
        if (t == 0) dw2 = fminf(dw2, BOUNDARY);   // clip row H (elem 0 of T2 block)
        float dwo = dTw[i3 + 2 * HH + t];

        float T1 = sigm(xm1 + sigm(dw1 * di));
        float T2 = sigm(xm2 + sigm(dw2 * di));
        float gi = sigm(gi_pre + cinw[i1 + t] * ct);

        float gT1 = gi * T1;
        float c_tilde = (1.f - gT1) * ct + gT1 * gc;
        float c_new = (1.f - gi) * ct + gi * T2 * gc;
        // del_To = dwo * delta  (this term was missing *di in the last round)
        float go = sigm(go_pre + coutw[i1 + t] * c_tilde + dwo * di);
        float h_new = go * tanhf(c_tilde);

        outH[i1 + t] = h_new;
        outC[i1 + t] = c_new;
    }
}

// Pass A: 32 gathered rows per block -> 64 partial sums per block.
__global__ __launch_bounds__(256) void reduceA(const float* __restrict__ outC,
                                               const int* __restrict__ feat_idx,
                                               float* __restrict__ partial, int n) {
    __shared__ float s[256];
    const int b = blockIdx.x, t = threadIdx.x;
    const int h = t & 63, g = t >> 6;
    const int rend = min(n, (b + 1) * 32);
    float acc = 0.f;
    for (int r = b * 32 + g; r < rend; r += 4)
        acc += outC[(size_t)feat_idx[r] * HH + h];
    s[t] = acc;
    __syncthreads();
    if (t < HH) partial[b * HH + h] = s[h] + s[64 + h] + s[128 + h] + s[192 + h];
}

// Pass B: combine block partials, divide by n.
__global__ __launch_bounds__(256) void reduceB(const float* __restrict__ partial,
                                               float* __restrict__ outM,
                                               int nblocks, int n) {
    __shared__ float s[256];
    const int t = threadIdx.x, h = t & 63, g = t >> 6;
    float acc = 0.f;
    for (int b = g; b < nblocks; b += 4) acc += partial[(size_t)b * HH + h];
    s[t] = acc;
    __syncthreads();
    if (t < HH) outM[h] = (s[h] + s[64 + h] + s[128 + h] + s[192 + h]) / (float)n;
}

// Fallback if d_ws too small: single-block deterministic reduce.
__global__ __launch_bounds__(256) void reduceAll(const float* __restrict__ outC,
                                                 const int* __restrict__ feat_idx,
                                                 float* __restrict__ outM, int n) {
    __shared__ float s[256];
    const int t = threadIdx.x, h = t & 63, g = t >> 6;
    float acc = 0.f;
    for (int r = g; r < n; r += 4)
        acc += outC[(size_t)feat_idx[r] * HH + h];
    s[t] = acc;
    __syncthreads();
    if (t < HH) outM[h] = (s[h] + s[64 + h] + s[128 + h] + s[192 + h]) / (float)n;
}

extern "C" void kernel_launch(void* const* d_in, const int* in_sizes, int n_in,
                              void* d_out, int out_size, void* d_ws, size_t ws_size,
                              hipStream_t stream) {
    const float* X        = (const float*)d_in[0];
    const float* delta    = (const float*)d_in[1];
    const float* Ht       = (const float*)d_in[2];
    const float* c_t      = (const float*)d_in[3];
    const float* c_global = (const float*)d_in[4];
    const float* W        = (const float*)d_in[5];
    const float* bias     = (const float*)d_in[6];
    const float* xTw      = (const float*)d_in[7];
    const float* xTb      = (const float*)d_in[8];
    const float* dTw      = (const float*)d_in[9];
    const float* cinw     = (const float*)d_in[10];
    const float* coutw    = (const float*)d_in[11];
    const int*   feat_idx = (const int*)d_in[12];

    const int F  = in_sizes[0];
    const int n  = in_sizes[12];
    const int FH = F * HH;

    float* out  = (float*)d_out;
    float* outH = out;            // [F,H]
    float* outC = out + FH;       // [F,H]
    float* outM = out + 2 * FH;   // [H]

    // init: zero H_curr, copy c_global
    {
        int fh4 = FH / 4;
        int blocks = (fh4 + 255) / 256;
        if (blocks > 2048) blocks = 2048;
        init_kernel<<<blocks, 256, 0, stream>>>(outH, outC, c_global, fh4);
    }

    // main
    lstm_main<<<n, 256, 0, stream>>>(X, delta, Ht, c_t, W, bias, xTw, xTb,
                                     dTw, cinw, coutw, feat_idx, outH, outC);

    // mean reduction (deterministic)
    int nA = (n + 31) / 32;
    if (ws_size >= (size_t)nA * HH * sizeof(float)) {
        float* partial = (float*)d_ws;
        reduceA<<<nA, 256, 0, stream>>>(outC, feat_idx, partial, n);
        reduceB<<<1, 256, 0, stream>>>(partial, outM, nA, n);
    } else {
        reduceAll<<<1, 256, 0, stream>>>(outC, feat_idx, outM, n);
    }
}

// Round 3
// 110.649 us; speedup vs baseline: 1.0144x; 1.0144x over previous
//
#include <hip/hip_runtime.h>
#include <cstdint>
#include <cstddef>

#define HH 64          // H
#define G3 192         // 3H
#define G2 128         // 2H
#define ROWF 12480     // floats per lstm_weights row = 3H*(H+1)
#define CHF 2080       // floats per staged chunk = 32 rows x 65
#define BOUNDARY (-0.01f)

__device__ __forceinline__ float sigm(float x) { return 1.0f / (1.0f + __expf(-x)); }

__device__ __forceinline__ void load_lds16(const float* g, float* l) {
    __builtin_amdgcn_global_load_lds(
        (const __attribute__((address_space(1))) void*)g,
        (__attribute__((address_space(3))) void*)l,
        16, 0, 0);
}

// Zero H_curr, copy c_global into c_global_new.
__global__ __launch_bounds__(256) void init_kernel(float* __restrict__ outH,
                                                   float* __restrict__ outC,
                                                   const float* __restrict__ c_global,
                                                   int fh4) {
    int idx = blockIdx.x * 256 + threadIdx.x;
    int stride = gridDim.x * 256;
    for (int k = idx; k < fh4; k += stride) {
        ((float4*)outH)[k] = make_float4(0.f, 0.f, 0.f, 0.f);
        ((float4*)outC)[k] = ((const float4*)c_global)[k];
    }
}

// Two blocks per gathered feature: block handles h in [hb, hb+32).
// Needs weight rows {h, 64+h, 128+h : h in half} = 3 contiguous 32-row chunks.
__global__ __launch_bounds__(256) void lstm_main(
    const float* __restrict__ X, const float* __restrict__ delta,
    const float* __restrict__ Ht, const float* __restrict__ c_t,
    const float* __restrict__ W, const float* __restrict__ bias,
    const float* __restrict__ xTw, const float* __restrict__ xTb,
    const float* __restrict__ dTw, const float* __restrict__ cinw,
    const float* __restrict__ coutw, const int* __restrict__ feat_idx,
    float* __restrict__ outH, float* __restrict__ outC) {

    __shared__ float w[3 * CHF];   // 24,960 B
    __shared__ float inp[72];      // [x, h_prev(64)]
    __shared__ float co[96];

    const int t    = threadIdx.x;
    const int b    = blockIdx.x;
    const int f    = b >> 1;
    const int hb   = (b & 1) << 5;        // 0 or 32
    const int i    = feat_idx[f];
    const int lane = t & 63;
    const int wv   = t >> 6;

    const size_t i1 = (size_t)i * HH;
    const size_t i2 = (size_t)i * G2;
    const size_t i3 = (size_t)i * G3;

    // ---- prefetch all small operands into registers (drained at the barrier) ----
    float xi = 0.f, di = 0.f, ct = 0.f, cinv = 0.f, coutv = 0.f;
    float xw1 = 0.f, xw2 = 0.f, xb1 = 0.f, xb2 = 0.f;
    float dw1 = 0.f, dw2 = 0.f, dwo = 0.f, bv = 0.f;
    if (t < 32) {
        const int h = hb + t;
        xi   = X[i];
        di   = delta[i];
        ct   = c_t[h];
        cinv = cinw[i1 + h];
        coutv = coutw[i1 + h];
        xw1  = xTw[i2 + h];
        xw2  = xTw[i2 + HH + h];
        xb1  = xTb[i2 + h];
        xb2  = xTb[i2 + HH + h];
        dw1  = dTw[i3 + h];
        dw2  = dTw[i3 + HH + h];
        dwo  = dTw[i3 + 2 * HH + h];
    }
    if (t < 96) {
        const int ch = t >> 5, idx = t & 31;
        bv = bias[i3 + ch * HH + hb + idx];
    }

    // stage cur_input = [x, h_prev]
    if (t == 0) inp[0] = X[i];
    if (wv == 1) inp[1 + lane] = Ht[i1 + lane];

    // ---- stage 3 weight chunks: 27 wave-load slots across 4 waves ----
    const float* wrow = W + (size_t)i * ROWF;
    for (int s = wv; s < 27; s += 4) {
        const int ch  = s / 9;
        const int off = s % 9;
        const int fl  = off * 256 + lane * 4;   // float offset within chunk
        if (fl < CHF)
            load_lds16(wrow + (size_t)(64 * ch + hb) * 65 + fl,
                       &w[ch * CHF + off * 256]);
    }
    __syncthreads();

    // ---- matvec: 96 threads, one cur_out element each ----
    if (t < 96) {
        const int ch = t >> 5, idx = t & 31;
        const float* wr = &w[ch * CHF + idx * 65];
        float acc = bv;
        #pragma unroll
        for (int k = 0; k < 65; ++k) acc = fmaf(wr[k], inp[k], acc);
        co[t] = acc;
    }
    __syncthreads();

    // ---- gate math: 32 threads ----
    if (t < 32) {
        const int h = hb + t;
        float gi_pre = co[t];
        float go_pre = co[32 + t];
        float gc     = tanhf(co[64 + t]);

        float xm1 = fmaf(xw1, xi, xb1);
        float xm2 = fmaf(xw2, xi, xb2);
        // clip delT weight at row H=64 (element 0 of T2 block)
        if (h == 0) dw2 = fminf(dw2, BOUNDARY);

        float T1 = sigm(xm1 + sigm(dw1 * di));
        float T2 = sigm(xm2 + sigm(dw2 * di));
        float gi = sigm(gi_pre + cinv * ct);

        float gT1     = gi * T1;
        float c_tilde = (1.f - gT1) * ct + gT1 * gc;
        float c_new   = (1.f - gi) * ct + gi * T2 * gc;
        float go      = sigm(go_pre + coutv * c_tilde + dwo * di);

        outH[i1 + h] = go * tanhf(c_tilde);
        outC[i1 + h] = c_new;
    }
}

// Stage 1: 128 gathered rows per block -> 64 partials per block.
__global__ __launch_bounds__(256) void reduceA(const float* __restrict__ outC,
                                               const int* __restrict__ feat_idx,
                                               float* __restrict__ partial, int n) {
    __shared__ float s[256];
    const int b = blockIdx.x, t = threadIdx.x;
    const int h = t & 63, g = t >> 6;
    const int rend = min(n, (b + 1) * 128);
    float acc = 0.f;
    for (int r = b * 128 + g; r < rend; r += 4)
        acc += outC[(size_t)feat_idx[r] * HH + h];
    s[t] = acc;
    __syncthreads();
    if (t < HH) partial[b * HH + h] = s[h] + s[64 + h] + s[128 + h] + s[192 + h];
}

// Stage 2: combine block partials, divide by n.
__global__ __launch_bounds__(256) void reduceB(const float* __restrict__ partial,
                                               float* __restrict__ outM,
                                               int nblocks, int n) {
    __shared__ float s[256];
    const int t = threadIdx.x, h = t & 63, g = t >> 6;
    float acc = 0.f;
    for (int b = g; b < nblocks; b += 4) acc += partial[(size_t)b * HH + h];
    s[t] = acc;
    __syncthreads();
    if (t < HH) outM[h] = (s[h] + s[64 + h] + s[128 + h] + s[192 + h]) / (float)n;
}

// Fallback if d_ws too small: single-block deterministic reduce.
__global__ __launch_bounds__(256) void reduceAll(const float* __restrict__ outC,
                                                 const int* __restrict__ feat_idx,
                                                 float* __restrict__ outM, int n) {
    __shared__ float s[256];
    const int t = threadIdx.x, h = t & 63, g = t >> 6;
    float acc = 0.f;
    for (int r = g; r < n; r += 4)
        acc += outC[(size_t)feat_idx[r] * HH + h];
    s[t] = acc;
    __syncthreads();
    if (t < HH) outM[h] = (s[h] + s[64 + h] + s[128 + h] + s[192 + h]) / (float)n;
}

extern "C" void kernel_launch(void* const* d_in, const int* in_sizes, int n_in,
                              void* d_out, int out_size, void* d_ws, size_t ws_size,
                              hipStream_t stream) {
    const float* X        = (const float*)d_in[0];
    const float* delta    = (const float*)d_in[1];
    const float* Ht       = (const float*)d_in[2];
    const float* c_t      = (const float*)d_in[3];
    const float* c_global = (const float*)d_in[4];
    const float* W        = (const float*)d_in[5];
    const float* bias     = (const float*)d_in[6];
    const float* xTw      = (const float*)d_in[7];
    const float* xTb      = (const float*)d_in[8];
    const float* dTw      = (const float*)d_in[9];
    const float* cinw     = (const float*)d_in[10];
    const float* coutw    = (const float*)d_in[11];
    const int*   feat_idx = (const int*)d_in[12];

    const int F  = in_sizes[0];
    const int n  = in_sizes[12];
    const int FH = F * HH;

    float* out  = (float*)d_out;
    float* outH = out;            // [F,H]
    float* outC = out + FH;       // [F,H]
    float* outM = out + 2 * FH;   // [H]

    // init: zero H_curr, copy c_global
    {
        int fh4 = FH / 4;
        int blocks = (fh4 + 255) / 256;
        if (blocks > 2048) blocks = 2048;
        init_kernel<<<blocks, 256, 0, stream>>>(outH, outC, c_global, fh4);
    }

    // main: 2 blocks per gathered feature
    lstm_main<<<2 * n, 256, 0, stream>>>(X, delta, Ht, c_t, W, bias, xTw, xTb,
                                         dTw, cinw, coutw, feat_idx, outH, outC);

    // mean reduction (deterministic, 2-stage)
    int nA = (n + 127) / 128;
    if (ws_size >= (size_t)nA * HH * sizeof(float)) {
        float* partial = (float*)d_ws;
        reduceA<<<nA, 256, 0, stream>>>(outC, feat_idx, partial, n);
        reduceB<<<1, 256, 0, stream>>>(partial, outM, nA, n);
    } else {
        reduceAll<<<1, 256, 0, stream>>>(outC, feat_idx, outM, n);
    }
}